// Round 8
// baseline (536.456 us; speedup 1.0000x reference)
//
#include <hip/hip_runtime.h>
#include <math.h>

// ---------------- problem constants ----------------
#define NHID   256
#define NEMB   224

// ---------------- workspace layout (float indices) ----------------
constexpr int OFF_BASE = 0;                          // 768   (b_ih + uid proj)
constexpr int OFF_WDP  = 768;                        // 7*768
constexpr int OFF_HRP  = OFF_WDP + 7*768;            // 24*768
constexpr int OFF_XPH  = OFF_HRP + 24*768;           // 32*64*768
constexpr int OFF_XPC  = OFF_XPH + 32*64*768;        // 32*32*768
constexpr int OFF_HSH  = OFF_XPC + 32*32*768;        // 32*64*256
constexpr int OFF_HSC  = OFF_HSH + 32*64*256;        // 32*32*256
constexpr int OFF_GHL  = OFF_HSC + 32*32*256;        // 32*768
constexpr int OFF_QHH  = OFF_GHL + 32*768;           // 32*256
constexpr int OFF_HC   = OFF_QHH + 32*256;           // 4096*256
constexpr int OFF_KHH  = OFF_HC  + 4096*256;         // 32*64*256
constexpr int OFF_KHSH = OFF_KHH + 32*64*256;        // 32*32*256
constexpr int OFF_KHC  = OFF_KHSH+ 32*32*256;        // 4096*256
constexpr int OFF_QHC  = OFF_KHC + 4096*256;         // 4096*256
constexpr int OFF_HIST = OFF_QHC + 4096*256;         // 32*256
constexpr int OFF_CHID = OFF_HIST+ 32*256;           // 4096*256
constexpr int OFF_QH2  = OFF_CHID+ 4096*256;         // 4096*256
constexpr int OFF_KH2  = OFF_QH2 + 4096*256;         // 32*256
constexpr int OFF_SC   = OFF_KH2 + 32*256;           // 4096 scores
// W_hh packed fp16 (24576 uint4 = 393KB) ALIASES the KHH region: written by
// k_prep (pack blocks), consumed only by k_gru, then k_proj_intra overwrites KHH.
constexpr int OFF_W16  = OFF_KHH;                    // as uint32 index

__device__ __forceinline__ float sigm(float x) { return 1.0f / (1.0f + __expf(-x)); }
// fast tanh: exact at saturation, ~1e-7 rel err, ~5 instr vs ~40 for libm tanhf
__device__ __forceinline__ float tanhf_fast(float x) {
  return 1.f - 2.f / (__expf(2.f * x) + 1.f);
}

typedef _Float16 half2_t __attribute__((ext_vector_type(2)));

__device__ __forceinline__ float fdot2f(unsigned int a, unsigned int b, float c) {
#if __has_builtin(__builtin_amdgcn_fdot2)
  return __builtin_amdgcn_fdot2(__builtin_bit_cast(half2_t, a),
                                __builtin_bit_cast(half2_t, b), c, false);
#else
  half2_t x = __builtin_bit_cast(half2_t, a);
  half2_t y = __builtin_bit_cast(half2_t, b);
  return c + (float)x[0] * (float)y[0] + (float)x[1] * (float)y[1];
#endif
}

__device__ __forceinline__ unsigned int packh(float a, float b) {
  unsigned short lo = __builtin_bit_cast(unsigned short, (_Float16)a);
  unsigned short hi = __builtin_bit_cast(unsigned short, (_Float16)b);
  return (unsigned int)lo | ((unsigned int)hi << 16);
}

#define DOT4(acc, wv, hv) \
  acc = fdot2f((wv).x, (hv).x, acc); acc = fdot2f((wv).y, (hv).y, acc); \
  acc = fdot2f((wv).z, (hv).z, acc); acc = fdot2f((wv).w, (hv).w, acc);

// ================= K0: prep tables + W_hh fp16 pack (merged) =============================
// blk 0: base=b_ih+uid proj | 1..7: wd tables | 8..31: hr tables | 32..127: pack W_hh
__global__ __launch_bounds__(256) void k_prep(const int* uid, const float* uid_emb,
                                              const float* wde, const float* hre,
                                              const float* W_ih, const float* b_ih,
                                              const float* W_hh, float* ws) {
  __shared__ __align__(16) float ev[64];
  int blk = blockIdx.x, tid = threadIdx.x;
  if (blk >= 32) {                                 // pack W_hh
    int idx = (blk - 32) * 256 + tid;              // 0..24575
    int i4 = idx & 31, j = idx >> 5;
    const float4* p = (const float4*)(W_hh + j * 256 + i4 * 8);
    float4 a = p[0], b = p[1];
    uint4 o;
    o.x = packh(a.x, a.y); o.y = packh(a.z, a.w);
    o.z = packh(b.x, b.y); o.w = packh(b.z, b.w);
    ((uint4*)((unsigned int*)ws + OFF_W16))[i4 * 768 + j] = o;
    return;
  }
  if (blk == 0) {
    if (tid < 64) ev[tid] = uid_emb[uid[0] * 64 + tid];
    __syncthreads();
    #pragma unroll
    for (int jj = 0; jj < 3; ++jj) {
      int j = tid + jj * 256;
      float acc = b_ih[j];
      const float* wr = W_ih + j * NEMB;
      #pragma unroll
      for (int k = 0; k < 64; k += 4) {
        float4 w = *(const float4*)(wr + k);
        acc += ev[k]*w.x + ev[k+1]*w.y + ev[k+2]*w.z + ev[k+3]*w.w;
      }
      ws[OFF_BASE + j] = acc;
    }
  } else if (blk < 8) {
    int wd = blk - 1;
    if (tid < 16) ev[tid] = wde[wd * 16 + tid];
    __syncthreads();
    #pragma unroll
    for (int jj = 0; jj < 3; ++jj) {
      int j = tid + jj * 256;
      float acc = 0.f;
      const float* wr = W_ih + j * NEMB + 192;
      #pragma unroll
      for (int k = 0; k < 16; k += 4) {
        float4 w = *(const float4*)(wr + k);
        acc += ev[k]*w.x + ev[k+1]*w.y + ev[k+2]*w.z + ev[k+3]*w.w;
      }
      ws[OFF_WDP + wd * 768 + j] = acc;
    }
  } else {
    int hr = blk - 8;
    if (tid < 16) ev[tid] = hre[hr * 16 + tid];
    __syncthreads();
    #pragma unroll
    for (int jj = 0; jj < 3; ++jj) {
      int j = tid + jj * 256;
      float acc = 0.f;
      const float* wr = W_ih + j * NEMB + 208;
      #pragma unroll
      for (int k = 0; k < 16; k += 4) {
        float4 w = *(const float4*)(wr + k);
        acc += ev[k]*w.x + ev[k+1]*w.y + ev[k+2]*w.z + ev[k+3]*w.w;
      }
      ws[OFF_HRP + hr * 768 + j] = acc;
    }
  }
}

// ================= K1: x_proj rows (hist 2048 + curr 1024); 16 rows/block, W in LDS ======
__global__ __launch_bounds__(256) void k_xproj(const int* cur_tr, const int* hist_tr,
                                               const float* loc_emb, const float* W_ih,
                                               float* ws) {
  __shared__ float Ws[768][17];
  __shared__ float Xs[16][20];     // transposed: Xs[k][r]
  __shared__ int s_wd[16], s_hr[16], s_loc[16];
  int blk = blockIdx.x, tid = threadIdx.x;
  int r0 = blk * 16;

  if (tid < 16) {
    int row = r0 + tid;
    const int* tr; int idx;
    if (row < 2048) { tr = hist_tr; idx = row; } else { tr = cur_tr; idx = row - 2048; }
    s_loc[tid] = tr[idx * 3];
    s_wd[tid]  = tr[idx * 3 + 1];
    s_hr[tid]  = tr[idx * 3 + 2];
  }
  __syncthreads();

  float accA[16], accB[16], accC[16];
  #pragma unroll
  for (int r = 0; r < 16; ++r) { accA[r] = 0.f; accB[r] = 0.f; accC[r] = 0.f; }

  for (int kb = 0; kb < 8; ++kb) {
    for (int i = tid; i < 768 * 4; i += 256) {
      int j = i >> 2, q = (i & 3) * 4;
      float4 w = *(const float4*)&W_ih[j * NEMB + 64 + kb * 16 + q];
      Ws[j][q] = w.x; Ws[j][q+1] = w.y; Ws[j][q+2] = w.z; Ws[j][q+3] = w.w;
    }
    if (tid < 64) {
      int r = tid >> 2, q = (tid & 3) * 4;
      float4 x = *(const float4*)&loc_emb[s_loc[r] * 128 + kb * 16 + q];
      Xs[q][r] = x.x; Xs[q+1][r] = x.y; Xs[q+2][r] = x.z; Xs[q+3][r] = x.w;
    }
    __syncthreads();
    #pragma unroll
    for (int kk = 0; kk < 16; ++kk) {
      float wa = Ws[tid][kk], wb = Ws[tid + 256][kk], wc = Ws[tid + 512][kk];
      float4 x0 = *(const float4*)&Xs[kk][0];
      float4 x1 = *(const float4*)&Xs[kk][4];
      float4 x2 = *(const float4*)&Xs[kk][8];
      float4 x3 = *(const float4*)&Xs[kk][12];
      float xv[16] = {x0.x,x0.y,x0.z,x0.w, x1.x,x1.y,x1.z,x1.w,
                      x2.x,x2.y,x2.z,x2.w, x3.x,x3.y,x3.z,x3.w};
      #pragma unroll
      for (int r = 0; r < 16; ++r) {
        accA[r] += xv[r] * wa; accB[r] += xv[r] * wb; accC[r] += xv[r] * wc;
      }
    }
    __syncthreads();
  }

  float bA = ws[OFF_BASE + tid], bB = ws[OFF_BASE + 256 + tid], bC = ws[OFF_BASE + 512 + tid];
  for (int r = 0; r < 16; ++r) {
    int row = r0 + r;
    float* outp = (row < 2048) ? (ws + OFF_XPH + row * 768)
                               : (ws + OFF_XPC + (row - 2048) * 768);
    const float* wdp = ws + OFF_WDP + s_wd[r] * 768;
    const float* hrp = ws + OFF_HRP + s_hr[r] * 768;
    outp[tid]       = accA[r] + bA + wdp[tid]       + hrp[tid];
    outp[256 + tid] = accB[r] + bB + wdp[256 + tid] + hrp[256 + tid];
    outp[512 + tid] = accC[r] + bC + wdp[512 + tid] + hrp[512 + tid];
  }
}

// ================= K2: GRU scan — thread j owns gate rows {j, j+256, j+512} ==============
// 256 threads (4 waves, 1/SIMD). All gh components land in registers: no mid-step
// LDS round-trip; double-buffered h16 -> ONE barrier per step.
// blocks 0..31: history (T=64), tail qh = relu(h @ intra_w1.T)
// blocks 32..63: current (T=32), tail gh_last = b_hh + h @ W_hh.T
__global__ __launch_bounds__(256, 1) void k_gru(const float* b_hh, const float* intra_w1,
                                                float* ws) {
  __shared__ __align__(16) unsigned short h16[2][256];
  __shared__ __align__(16) float hfin[256];
  int w = blockIdx.x, tid = threadIdx.x;
  int T; const float* xp; float* hs;
  if (w < 32) { T = 64; xp = ws + OFF_XPH + w * 64 * 768; hs = ws + OFF_HSH + w * 64 * 256; }
  else        { T = 32; int b = w - 32; xp = ws + OFF_XPC + b * 32 * 768; hs = ws + OFF_HSC + b * 32 * 256; }

  // 3 weight rows per thread (r/z/n), coalesced loads from i4-interleaved pack
  uint4 wra[32], wrb[32], wrc[32];
  {
    const uint4* wp = (const uint4*)((const unsigned int*)ws + OFF_W16);
    #pragma unroll
    for (int i = 0; i < 32; ++i) {
      wra[i] = wp[i * 768 + tid];
      wrb[i] = wp[i * 768 + tid + 256];
      wrc[i] = wp[i * 768 + tid + 512];
    }
  }
  float bha = b_hh[tid], bhb = b_hh[tid + 256], bhc = b_hh[tid + 512];
  h16[0][tid] = 0;
  float hprev = 0.f;
  __syncthreads();

  int cur = 0;
  for (int t = 0; t < T; ++t) {
    float xr = xp[t * 768 + tid];          // issued early; consumed after dots
    float xz = xp[t * 768 + 256 + tid];
    float xn = xp[t * 768 + 512 + tid];
    const uint4* hp = (const uint4*)h16[cur];
    float a0 = bha, a1 = 0.f, b0 = bhb, b1 = 0.f, c0 = bhc, c1 = 0.f;
    #pragma unroll
    for (int i = 0; i < 32; i += 2) {
      uint4 h0 = hp[i];
      DOT4(a0, wra[i], h0) DOT4(b0, wrb[i], h0) DOT4(c0, wrc[i], h0)
      uint4 h1 = hp[i + 1];
      DOT4(a1, wra[i+1], h1) DOT4(b1, wrb[i+1], h1) DOT4(c1, wrc[i+1], h1)
    }
    float r  = sigm(xr + a0 + a1);
    float z  = sigm(xz + b0 + b1);
    float n  = tanhf_fast(xn + r * (c0 + c1));
    float hn = (1.f - z) * n + z * hprev;
    hprev = hn;
    hs[t * 256 + tid] = hn;
    h16[cur ^ 1][tid] = (unsigned short)__builtin_bit_cast(unsigned short, (_Float16)hn);
    __syncthreads();                        // publish h16 for next step
    cur ^= 1;
  }

  if (w < 32) {
    hfin[tid] = hprev;
    __syncthreads();
    float acc = 0.f;
    const float* r1 = intra_w1 + tid * 256;
    #pragma unroll 16
    for (int k = 0; k < 256; k += 4) {
      float4 wv = *(const float4*)(r1 + k);
      float4 hv = *(const float4*)&hfin[k];
      acc += hv.x*wv.x + hv.y*wv.y + hv.z*wv.z + hv.w*wv.w;
    }
    ws[OFF_QHH + w * 256 + tid] = fmaxf(acc, 0.f);
  } else {
    // gh_last from final h (h16[cur] holds it after the last toggle)
    const uint4* hp = (const uint4*)h16[cur];
    float a0 = bha, a1 = 0.f, b0 = bhb, b1 = 0.f, c0 = bhc, c1 = 0.f;
    #pragma unroll
    for (int i = 0; i < 32; i += 2) {
      uint4 h0 = hp[i];
      DOT4(a0, wra[i], h0) DOT4(b0, wrb[i], h0) DOT4(c0, wrc[i], h0)
      uint4 h1 = hp[i + 1];
      DOT4(a1, wra[i+1], h1) DOT4(b1, wrb[i+1], h1) DOT4(c1, wrc[i+1], h1)
    }
    int b = w - 32;
    ws[OFF_GHL + b * 768 + tid]       = a0 + a1;
    ws[OFF_GHL + b * 768 + 256 + tid] = b0 + b1;
    ws[OFF_GHL + b * 768 + 512 + tid] = c0 + c1;
  }
}

// ================= K3: candidate final GRU step (16 rows/block, W in LDS) ================
__global__ __launch_bounds__(256) void k_cand(const int* cur_tr, const int* cand_set,
                                              const float* loc_emb, const float* W_ih,
                                              float* ws) {
  __shared__ float Ws[768][17];
  __shared__ float Xs[16][20];     // transposed
  int blk = blockIdx.x, tid = threadIdx.x;
  int r0 = blk * 16;
  int s = r0 >> 7;                 // 128 candidates per s, 16 | 128

  float accA[16], accB[16], accC[16];
  #pragma unroll
  for (int r = 0; r < 16; ++r) { accA[r] = 0.f; accB[r] = 0.f; accC[r] = 0.f; }

  for (int kb = 0; kb < 8; ++kb) {
    for (int i = tid; i < 768 * 4; i += 256) {
      int j = i >> 2, q = (i & 3) * 4;
      float4 w = *(const float4*)&W_ih[j * NEMB + 64 + kb * 16 + q];
      Ws[j][q] = w.x; Ws[j][q+1] = w.y; Ws[j][q+2] = w.z; Ws[j][q+3] = w.w;
    }
    if (tid < 64) {
      int r = tid >> 2, q = (tid & 3) * 4;
      float4 x = *(const float4*)&loc_emb[cand_set[r0 + r] * 128 + kb * 16 + q];
      Xs[q][r] = x.x; Xs[q+1][r] = x.y; Xs[q+2][r] = x.z; Xs[q+3][r] = x.w;
    }
    __syncthreads();
    #pragma unroll
    for (int kk = 0; kk < 16; ++kk) {
      float wa = Ws[tid][kk], wb = Ws[tid + 256][kk], wc = Ws[tid + 512][kk];
      float4 x0 = *(const float4*)&Xs[kk][0];
      float4 x1 = *(const float4*)&Xs[kk][4];
      float4 x2 = *(const float4*)&Xs[kk][8];
      float4 x3 = *(const float4*)&Xs[kk][12];
      float xv[16] = {x0.x,x0.y,x0.z,x0.w, x1.x,x1.y,x1.z,x1.w,
                      x2.x,x2.y,x2.z,x2.w, x3.x,x3.y,x3.z,x3.w};
      #pragma unroll
      for (int r = 0; r < 16; ++r) {
        accA[r] += xv[r] * wa; accB[r] += xv[r] * wb; accC[r] += xv[r] * wc;
      }
    }
    __syncthreads();
  }

  int last = s * 32 + 31;
  int wd = cur_tr[last * 3 + 1], hr = cur_tr[last * 3 + 2];
  const float* wdp = ws + OFF_WDP + wd * 768;
  const float* hrp = ws + OFF_HRP + hr * 768;
  float xbA = ws[OFF_BASE + tid]       + wdp[tid]       + hrp[tid];
  float xbB = ws[OFF_BASE + 256 + tid] + wdp[256 + tid] + hrp[256 + tid];
  float xbC = ws[OFF_BASE + 512 + tid] + wdp[512 + tid] + hrp[512 + tid];
  float ghr = ws[OFF_GHL + s * 768 + tid];
  float ghz = ws[OFF_GHL + s * 768 + 256 + tid];
  float ghn = ws[OFF_GHL + s * 768 + 512 + tid];
  float hp  = ws[OFF_HSC + last * 256 + tid];

  for (int r = 0; r < 16; ++r) {
    float rr = sigm(xbA + accA[r] + ghr);
    float zz = sigm(xbB + accB[r] + ghz);
    float nn = tanhf_fast(xbC + accC[r] + ghn);
    float hn = (1.f - zz) * nn + zz * hp;
    ws[OFF_HC + (r0 + r) * 256 + tid] = hn;
  }
}

// ================= K4/K7 common: OUT[32 rows x 256] = relu(X @ W.T), W in LDS ============
__device__ __forceinline__ void proj_body(const float* in, float* out, const float* W,
                                          int r0, int tid) {
  __shared__ float Ws[256][33];
  __shared__ float Xs[32][36];     // transposed: Xs[k][r]
  int c0 = tid & 63, rg = (tid >> 6) * 8;
  float acc[4][8];
  #pragma unroll
  for (int c = 0; c < 4; ++c)
    #pragma unroll
    for (int r = 0; r < 8; ++r) acc[c][r] = 0.f;

  for (int kb = 0; kb < 8; ++kb) {
    for (int i = tid; i < 256 * 8; i += 256) {
      int j = i >> 3, q = (i & 7) * 4;
      float4 v = *(const float4*)&W[j * 256 + kb * 32 + q];
      Ws[j][q] = v.x; Ws[j][q+1] = v.y; Ws[j][q+2] = v.z; Ws[j][q+3] = v.w;
    }
    {
      int r = tid >> 3, q = (tid & 7) * 4;
      float4 v = *(const float4*)&in[(r0 + r) * 256 + kb * 32 + q];
      Xs[q][r] = v.x; Xs[q+1][r] = v.y; Xs[q+2][r] = v.z; Xs[q+3][r] = v.w;
    }
    __syncthreads();
    #pragma unroll
    for (int kk = 0; kk < 32; ++kk) {
      float w0 = Ws[c0][kk], w1 = Ws[c0 + 64][kk], w2 = Ws[c0 + 128][kk], w3 = Ws[c0 + 192][kk];
      float4 xa = *(const float4*)&Xs[kk][rg];
      float4 xb = *(const float4*)&Xs[kk][rg + 4];
      float xv[8] = {xa.x,xa.y,xa.z,xa.w, xb.x,xb.y,xb.z,xb.w};
      #pragma unroll
      for (int r = 0; r < 8; ++r) {
        acc[0][r] += xv[r] * w0; acc[1][r] += xv[r] * w1;
        acc[2][r] += xv[r] * w2; acc[3][r] += xv[r] * w3;
      }
    }
    __syncthreads();
  }
  #pragma unroll
  for (int c = 0; c < 4; ++c)
    for (int r = 0; r < 8; ++r)
      out[(r0 + rg + r) * 256 + c0 + c * 64] = fmaxf(acc[c][r], 0.f);
}

// blk<64: HSH->KHH | <96: HSC->KHSH | <224: HC->KHC | <352: HC->QHC
__global__ __launch_bounds__(256) void k_proj_intra(const float* intra_w1, const float* intra_w2,
                                                    float* ws) {
  int blk = blockIdx.x, tid = threadIdx.x;
  const float* in; float* out; const float* W; int r0;
  if (blk < 64)       { in = ws + OFF_HSH; out = ws + OFF_KHH;  W = intra_w2; r0 = blk * 32; }
  else if (blk < 96)  { in = ws + OFF_HSC; out = ws + OFF_KHSH; W = intra_w2; r0 = (blk - 64) * 32; }
  else if (blk < 224) { in = ws + OFF_HC;  out = ws + OFF_KHC;  W = intra_w2; r0 = (blk - 96) * 32; }
  else                { in = ws + OFF_HC;  out = ws + OFF_QHC;  W = intra_w1; r0 = (blk - 224) * 32; }
  proj_body(in, out, W, r0, tid);
}

// blk<128: CHID->QH2 (inter_w1) | blk==128: HIST->KH2 (inter_w2)
__global__ __launch_bounds__(256) void k_proj_inter(const float* inter_w1, const float* inter_w2,
                                                    float* ws) {
  int blk = blockIdx.x, tid = threadIdx.x;
  const float* in; float* out; const float* W; int r0;
  if (blk < 128) { in = ws + OFF_CHID; out = ws + OFF_QH2; W = inter_w1; r0 = blk * 32; }
  else           { in = ws + OFF_HIST; out = ws + OFF_KH2; W = inter_w2; r0 = 0; }
  proj_body(in, out, W, r0, tid);
}

// ================= K5: history intra attention -> hist_hidden ============================
__global__ __launch_bounds__(256) void k_hist_attn(const float* intra_out, float* ws) {
  __shared__ __align__(16) float a[64];
  int b = blockIdx.x, tid = threadIdx.x;
  int wv = tid >> 6, lane = tid & 63;
  const float* qh = ws + OFF_QHH + b * 256;
  const float* kh = ws + OFF_KHH + b * 64 * 256;
  const float* hs = ws + OFF_HSH + b * 64 * 256;

  float4 q4  = *(const float4*)&qh[lane * 4];
  float4 io4 = *(const float4*)&intra_out[lane * 4];
  for (int t = wv; t < 64; t += 4) {
    float4 k4 = *(const float4*)&kh[t * 256 + lane * 4];
    float p = tanhf_fast(q4.x + k4.x) * io4.x + tanhf_fast(q4.y + k4.y) * io4.y +
              tanhf_fast(q4.z + k4.z) * io4.z + tanhf_fast(q4.w + k4.w) * io4.w;
    #pragma unroll
    for (int off = 32; off; off >>= 1) p += __shfl_down(p, off);
    if (lane == 0) a[t] = p;
  }
  __syncthreads();
  if (tid < 64) {
    float v = a[tid];
    float m = v;
    #pragma unroll
    for (int off = 32; off; off >>= 1) m = fmaxf(m, __shfl_xor(m, off));
    float e = __expf(v - m);
    float ssum = e;
    #pragma unroll
    for (int off = 32; off; off >>= 1) ssum += __shfl_xor(ssum, off);
    a[tid] = e / ssum;
  }
  __syncthreads();
  float acc = 0.f;
  for (int t = 0; t < 64; ++t) acc += a[t] * hs[t * 256 + tid];
  ws[OFF_HIST + b * 256 + tid] = acc;
}

// ================= K6: candidate intra attention -> cand_hidden (1 wave/row) =============
__global__ __launch_bounds__(64) void k_cand_attn(const float* intra_out, float* ws) {
  int bId = blockIdx.x;
  int s = bId >> 7;
  int lane = threadIdx.x;
  const float* qh  = ws + OFF_QHC  + bId * 256;
  const float* khs = ws + OFF_KHSH + s * 32 * 256;
  const float* khc = ws + OFF_KHC  + bId * 256;
  const float* hsc = ws + OFF_HSC  + s * 32 * 256;
  const float* hc  = ws + OFF_HC   + bId * 256;

  float4 q4  = *(const float4*)&qh[lane * 4];
  float4 io4 = *(const float4*)&intra_out[lane * 4];
  float aa[33];
  float m = -1e30f;
  for (int t = 0; t < 33; ++t) {
    const float* kk = (t < 32) ? &khs[t * 256] : khc;
    float4 k4 = *(const float4*)&kk[lane * 4];
    float p = tanhf_fast(q4.x + k4.x) * io4.x + tanhf_fast(q4.y + k4.y) * io4.y +
              tanhf_fast(q4.z + k4.z) * io4.z + tanhf_fast(q4.w + k4.w) * io4.w;
    #pragma unroll
    for (int off = 32; off; off >>= 1) p += __shfl_xor(p, off);
    aa[t] = p;
    m = fmaxf(m, p);
  }
  float ssum = 0.f;
  #pragma unroll
  for (int t = 0; t < 33; ++t) { aa[t] = __expf(aa[t] - m); ssum += aa[t]; }
  float inv = 1.f / ssum;
  float ax = 0.f, ay = 0.f, az = 0.f, aw = 0.f;
  for (int t = 0; t < 32; ++t) {
    float wt = aa[t] * inv;
    float4 hv = *(const float4*)&hsc[t * 256 + lane * 4];
    ax += wt * hv.x; ay += wt * hv.y; az += wt * hv.z; aw += wt * hv.w;
  }
  {
    float wt = aa[32] * inv;
    float4 hv = *(const float4*)&hc[lane * 4];
    ax += wt * hv.x; ay += wt * hv.y; az += wt * hv.z; aw += wt * hv.w;
  }
  float4 o; o.x = ax; o.y = ay; o.z = az; o.w = aw;
  *(float4*)&ws[OFF_CHID + bId * 256 + lane * 4] = o;
}

// ================= K8: inter attention -> moving (to d_out) + scores =====================
__global__ __launch_bounds__(64) void k_inter_attn(const float* inter_out, const float* score_w,
                                                   float* ws, float* d_out) {
  int bId = blockIdx.x;
  int lane = threadIdx.x;
  const float* qh   = ws + OFF_QH2 + bId * 256;
  const float* kh2  = ws + OFF_KH2;
  const float* hist = ws + OFF_HIST;

  float4 q4  = *(const float4*)&qh[lane * 4];
  float4 io4 = *(const float4*)&inter_out[lane * 4];
  float aa[32];
  float m = -1e30f;
  for (int t = 0; t < 32; ++t) {
    float4 k4 = *(const float4*)&kh2[t * 256 + lane * 4];
    float p = tanhf_fast(q4.x + k4.x) * io4.x + tanhf_fast(q4.y + k4.y) * io4.y +
              tanhf_fast(q4.z + k4.z) * io4.z + tanhf_fast(q4.w + k4.w) * io4.w;
    #pragma unroll
    for (int off = 32; off; off >>= 1) p += __shfl_xor(p, off);
    aa[t] = p;
    m = fmaxf(m, p);
  }
  float ssum = 0.f;
  #pragma unroll
  for (int t = 0; t < 32; ++t) { aa[t] = __expf(aa[t] - m); ssum += aa[t]; }
  float inv = 1.f / ssum;
  float ax = 0.f, ay = 0.f, az = 0.f, aw = 0.f;
  for (int t = 0; t < 32; ++t) {
    float wt = aa[t] * inv;
    float4 hv = *(const float4*)&hist[t * 256 + lane * 4];
    ax += wt * hv.x; ay += wt * hv.y; az += wt * hv.z; aw += wt * hv.w;
  }
  float4 o; o.x = ax; o.y = ay; o.z = az; o.w = aw;
  *(float4*)&d_out[4096 + bId * 256 + lane * 4] = o;
  float4 sw = *(const float4*)&score_w[lane * 4];
  float sc = ax*sw.x + ay*sw.y + az*sw.z + aw*sw.w;
  #pragma unroll
  for (int off = 32; off; off >>= 1) sc += __shfl_xor(sc, off);
  if (lane == 0) ws[OFF_SC + bId] = sc;
}

// ================= K9: probs = softmax over C=128 per s ==================================
__global__ __launch_bounds__(64) void k_probs(const float* ws, float* d_out) {
  int s = blockIdx.x, lane = threadIdx.x;
  float v0 = ws[OFF_SC + s * 128 + lane];
  float v1 = ws[OFF_SC + s * 128 + 64 + lane];
  float m = fmaxf(v0, v1);
  #pragma unroll
  for (int off = 32; off; off >>= 1) m = fmaxf(m, __shfl_xor(m, off));
  float e0 = __expf(v0 - m), e1 = __expf(v1 - m);
  float ssum = e0 + e1;
  #pragma unroll
  for (int off = 32; off; off >>= 1) ssum += __shfl_xor(ssum, off);
  float inv = 1.f / ssum;
  d_out[s * 128 + lane] = e0 * inv;
  d_out[s * 128 + 64 + lane] = e1 * inv;
}

// ======================= launch =========================================================
extern "C" void kernel_launch(void* const* d_in, const int* in_sizes, int n_in,
                              void* d_out, int out_size, void* d_ws, size_t ws_size,
                              hipStream_t stream) {
  const int*   uid      = (const int*)  d_in[0];
  const int*   cur_tr   = (const int*)  d_in[1];
  const int*   hist_tr  = (const int*)  d_in[2];
  const int*   cand_set = (const int*)  d_in[3];
  const float* uid_emb  = (const float*)d_in[4];
  const float* loc_emb  = (const float*)d_in[5];
  const float* wde      = (const float*)d_in[6];
  const float* hre      = (const float*)d_in[7];
  const float* W_ih     = (const float*)d_in[8];
  const float* W_hh     = (const float*)d_in[9];
  const float* b_ih     = (const float*)d_in[10];
  const float* b_hh     = (const float*)d_in[11];
  const float* intra_w1 = (const float*)d_in[12];
  const float* intra_w2 = (const float*)d_in[13];
  const float* intra_out= (const float*)d_in[14];
  const float* inter_w1 = (const float*)d_in[15];
  const float* inter_w2 = (const float*)d_in[16];
  const float* inter_out= (const float*)d_in[17];
  const float* score_w  = (const float*)d_in[18];
  float* ws  = (float*)d_ws;
  float* out = (float*)d_out;

  hipLaunchKernelGGL(k_prep,       dim3(128),  dim3(256), 0, stream, uid, uid_emb, wde, hre, W_ih, b_ih, W_hh, ws);
  hipLaunchKernelGGL(k_xproj,      dim3(192),  dim3(256), 0, stream, cur_tr, hist_tr, loc_emb, W_ih, ws);
  hipLaunchKernelGGL(k_gru,        dim3(64),   dim3(256), 0, stream, b_hh, intra_w1, ws);
  hipLaunchKernelGGL(k_cand,       dim3(256),  dim3(256), 0, stream, cur_tr, cand_set, loc_emb, W_ih, ws);
  hipLaunchKernelGGL(k_proj_intra, dim3(352),  dim3(256), 0, stream, intra_w1, intra_w2, ws);
  hipLaunchKernelGGL(k_hist_attn,  dim3(32),   dim3(256), 0, stream, intra_out, ws);
  hipLaunchKernelGGL(k_cand_attn,  dim3(4096), dim3(64),  0, stream, intra_out, ws);
  hipLaunchKernelGGL(k_proj_inter, dim3(129),  dim3(256), 0, stream, inter_w1, inter_w2, ws);
  hipLaunchKernelGGL(k_inter_attn, dim3(4096), dim3(64),  0, stream, inter_out, score_w, ws, out);
  hipLaunchKernelGGL(k_probs,      dim3(32),   dim3(64),  0, stream, ws, out);
}

// Round 9
// 440.546 us; speedup vs baseline: 1.2177x; 1.2177x over previous
//
#include <hip/hip_runtime.h>
#include <math.h>

// ---------------- problem constants ----------------
#define NHID   256
#define NEMB   224

// ---------------- workspace layout (float indices) ----------------
constexpr int OFF_BASE = 0;                          // 768   (b_ih + uid proj)
constexpr int OFF_WDP  = 768;                        // 7*768
constexpr int OFF_HRP  = OFF_WDP + 7*768;            // 24*768
constexpr int OFF_XPH  = OFF_HRP + 24*768;           // 32*64*768
constexpr int OFF_XPC  = OFF_XPH + 32*64*768;        // 32*32*768
constexpr int OFF_HSH  = OFF_XPC + 32*32*768;        // 32*64*256
constexpr int OFF_HSC  = OFF_HSH + 32*64*256;        // 32*32*256
constexpr int OFF_GHL  = OFF_HSC + 32*32*256;        // 32*768
constexpr int OFF_QHH  = OFF_GHL + 32*768;           // 32*256
constexpr int OFF_HC   = OFF_QHH + 32*256;           // 4096*256
constexpr int OFF_KHH  = OFF_HC  + 4096*256;         // 32*64*256
constexpr int OFF_KHSH = OFF_KHH + 32*64*256;        // 32*32*256
constexpr int OFF_KHC  = OFF_KHSH+ 32*32*256;        // 4096*256
constexpr int OFF_QHC  = OFF_KHC + 4096*256;         // 4096*256
constexpr int OFF_HIST = OFF_QHC + 4096*256;         // 32*256
constexpr int OFF_CHID = OFF_HIST+ 32*256;           // 4096*256
constexpr int OFF_QH2  = OFF_CHID+ 4096*256;         // 4096*256
constexpr int OFF_KH2  = OFF_QH2 + 4096*256;         // 32*256
constexpr int OFF_SC   = OFF_KH2 + 32*256;           // 4096 scores
// W_hh packed fp16 (24576 uint4 = 393KB) ALIASES the KHH region: written by
// k_prep (pack blocks), consumed only by k_gru, then k_proj_intra overwrites KHH.
constexpr int OFF_W16  = OFF_KHH;                    // as uint32 index

__device__ __forceinline__ float sigm(float x) { return 1.0f / (1.0f + __expf(-x)); }
// fast tanh: exact at saturation, ~1e-7 rel err (validated R7: absmax unchanged)
__device__ __forceinline__ float tanhf_fast(float x) {
  return 1.f - 2.f / (__expf(2.f * x) + 1.f);
}

typedef _Float16 half2_t __attribute__((ext_vector_type(2)));

__device__ __forceinline__ float fdot2f(unsigned int a, unsigned int b, float c) {
#if __has_builtin(__builtin_amdgcn_fdot2)
  return __builtin_amdgcn_fdot2(__builtin_bit_cast(half2_t, a),
                                __builtin_bit_cast(half2_t, b), c, false);
#else
  half2_t x = __builtin_bit_cast(half2_t, a);
  half2_t y = __builtin_bit_cast(half2_t, b);
  return c + (float)x[0] * (float)y[0] + (float)x[1] * (float)y[1];
#endif
}

__device__ __forceinline__ unsigned int packh(float a, float b) {
  unsigned short lo = __builtin_bit_cast(unsigned short, (_Float16)a);
  unsigned short hi = __builtin_bit_cast(unsigned short, (_Float16)b);
  return (unsigned int)lo | ((unsigned int)hi << 16);
}

// ================= K0: prep tables + W_hh fp16 pack (merged; validated R7) ===============
// blk 0: base=b_ih+uid proj | 1..7: wd tables | 8..31: hr tables | 32..127: pack W_hh
__global__ __launch_bounds__(256) void k_prep(const int* uid, const float* uid_emb,
                                              const float* wde, const float* hre,
                                              const float* W_ih, const float* b_ih,
                                              const float* W_hh, float* ws) {
  __shared__ __align__(16) float ev[64];
  int blk = blockIdx.x, tid = threadIdx.x;
  if (blk >= 32) {                                 // pack W_hh
    int idx = (blk - 32) * 256 + tid;              // 0..24575
    int i4 = idx & 31, j = idx >> 5;
    const float4* p = (const float4*)(W_hh + j * 256 + i4 * 8);
    float4 a = p[0], b = p[1];
    uint4 o;
    o.x = packh(a.x, a.y); o.y = packh(a.z, a.w);
    o.z = packh(b.x, b.y); o.w = packh(b.z, b.w);
    ((uint4*)((unsigned int*)ws + OFF_W16))[i4 * 768 + j] = o;
    return;
  }
  if (blk == 0) {
    if (tid < 64) ev[tid] = uid_emb[uid[0] * 64 + tid];
    __syncthreads();
    #pragma unroll
    for (int jj = 0; jj < 3; ++jj) {
      int j = tid + jj * 256;
      float acc = b_ih[j];
      const float* wr = W_ih + j * NEMB;
      #pragma unroll
      for (int k = 0; k < 64; k += 4) {
        float4 w = *(const float4*)(wr + k);
        acc += ev[k]*w.x + ev[k+1]*w.y + ev[k+2]*w.z + ev[k+3]*w.w;
      }
      ws[OFF_BASE + j] = acc;
    }
  } else if (blk < 8) {
    int wd = blk - 1;
    if (tid < 16) ev[tid] = wde[wd * 16 + tid];
    __syncthreads();
    #pragma unroll
    for (int jj = 0; jj < 3; ++jj) {
      int j = tid + jj * 256;
      float acc = 0.f;
      const float* wr = W_ih + j * NEMB + 192;
      #pragma unroll
      for (int k = 0; k < 16; k += 4) {
        float4 w = *(const float4*)(wr + k);
        acc += ev[k]*w.x + ev[k+1]*w.y + ev[k+2]*w.z + ev[k+3]*w.w;
      }
      ws[OFF_WDP + wd * 768 + j] = acc;
    }
  } else {
    int hr = blk - 8;
    if (tid < 16) ev[tid] = hre[hr * 16 + tid];
    __syncthreads();
    #pragma unroll
    for (int jj = 0; jj < 3; ++jj) {
      int j = tid + jj * 256;
      float acc = 0.f;
      const float* wr = W_ih + j * NEMB + 208;
      #pragma unroll
      for (int k = 0; k < 16; k += 4) {
        float4 w = *(const float4*)(wr + k);
        acc += ev[k]*w.x + ev[k+1]*w.y + ev[k+2]*w.z + ev[k+3]*w.w;
      }
      ws[OFF_HRP + hr * 768 + j] = acc;
    }
  }
}

// ================= K1: x_proj rows (hist 2048 + curr 1024); 16 rows/block, W in LDS ======
__global__ __launch_bounds__(256) void k_xproj(const int* cur_tr, const int* hist_tr,
                                               const float* loc_emb, const float* W_ih,
                                               float* ws) {
  __shared__ float Ws[768][17];
  __shared__ float Xs[16][20];     // transposed: Xs[k][r]
  __shared__ int s_wd[16], s_hr[16], s_loc[16];
  int blk = blockIdx.x, tid = threadIdx.x;
  int r0 = blk * 16;

  if (tid < 16) {
    int row = r0 + tid;
    const int* tr; int idx;
    if (row < 2048) { tr = hist_tr; idx = row; } else { tr = cur_tr; idx = row - 2048; }
    s_loc[tid] = tr[idx * 3];
    s_wd[tid]  = tr[idx * 3 + 1];
    s_hr[tid]  = tr[idx * 3 + 2];
  }
  __syncthreads();

  float accA[16], accB[16], accC[16];
  #pragma unroll
  for (int r = 0; r < 16; ++r) { accA[r] = 0.f; accB[r] = 0.f; accC[r] = 0.f; }

  for (int kb = 0; kb < 8; ++kb) {
    for (int i = tid; i < 768 * 4; i += 256) {
      int j = i >> 2, q = (i & 3) * 4;
      float4 w = *(const float4*)&W_ih[j * NEMB + 64 + kb * 16 + q];
      Ws[j][q] = w.x; Ws[j][q+1] = w.y; Ws[j][q+2] = w.z; Ws[j][q+3] = w.w;
    }
    if (tid < 64) {
      int r = tid >> 2, q = (tid & 3) * 4;
      float4 x = *(const float4*)&loc_emb[s_loc[r] * 128 + kb * 16 + q];
      Xs[q][r] = x.x; Xs[q+1][r] = x.y; Xs[q+2][r] = x.z; Xs[q+3][r] = x.w;
    }
    __syncthreads();
    #pragma unroll
    for (int kk = 0; kk < 16; ++kk) {
      float wa = Ws[tid][kk], wb = Ws[tid + 256][kk], wc = Ws[tid + 512][kk];
      float4 x0 = *(const float4*)&Xs[kk][0];
      float4 x1 = *(const float4*)&Xs[kk][4];
      float4 x2 = *(const float4*)&Xs[kk][8];
      float4 x3 = *(const float4*)&Xs[kk][12];
      float xv[16] = {x0.x,x0.y,x0.z,x0.w, x1.x,x1.y,x1.z,x1.w,
                      x2.x,x2.y,x2.z,x2.w, x3.x,x3.y,x3.z,x3.w};
      #pragma unroll
      for (int r = 0; r < 16; ++r) {
        accA[r] += xv[r] * wa; accB[r] += xv[r] * wb; accC[r] += xv[r] * wc;
      }
    }
    __syncthreads();
  }

  float bA = ws[OFF_BASE + tid], bB = ws[OFF_BASE + 256 + tid], bC = ws[OFF_BASE + 512 + tid];
  for (int r = 0; r < 16; ++r) {
    int row = r0 + r;
    float* outp = (row < 2048) ? (ws + OFF_XPH + row * 768)
                               : (ws + OFF_XPC + (row - 2048) * 768);
    const float* wdp = ws + OFF_WDP + s_wd[r] * 768;
    const float* hrp = ws + OFF_HRP + s_hr[r] * 768;
    outp[tid]       = accA[r] + bA + wdp[tid]       + hrp[tid];
    outp[256 + tid] = accB[r] + bB + wdp[256 + tid] + hrp[256 + tid];
    outp[512 + tid] = accC[r] + bC + wdp[512 + tid] + hrp[512 + tid];
  }
}

// ================= K2: GRU scans — R6 structure (measured 94 µs; VGPR 84) ================
// 768 threads, thread j owns gate row j; wreg[32] = 128 VGPR of fp16 weights.
// blocks 0..31: history (T=64), tail qh | blocks 32..63: current (T=32), tail gh_last
__global__ __launch_bounds__(768) void k_gru(const float* b_hh, const float* intra_w1,
                                             float* ws) {
  __shared__ __align__(16) float gh[768];
  __shared__ __align__(16) float h32[256];
  __shared__ __align__(16) unsigned short h16[256];
  int w = blockIdx.x, tid = threadIdx.x;
  int T; const float* xp; float* hs;
  if (w < 32) { T = 64; xp = ws + OFF_XPH + w * 64 * 768; hs = ws + OFF_HSH + w * 64 * 256; }
  else        { T = 32; int b = w - 32; xp = ws + OFF_XPC + b * 32 * 768; hs = ws + OFF_HSC + b * 32 * 256; }

  uint4 wreg[32];
  {
    const uint4* wp = (const uint4*)((const unsigned int*)ws + OFF_W16) + tid;
    #pragma unroll
    for (int i = 0; i < 32; ++i) wreg[i] = wp[i * 768];
  }
  float bh = b_hh[tid];
  if (tid < 256) { h32[tid] = 0.f; h16[tid] = 0; }
  __syncthreads();

  for (int t = 0; t < T; ++t) {
    float xr, xz, xn;
    if (tid < 256) {
      xr = xp[t * 768 + tid];
      xz = xp[t * 768 + 256 + tid];
      xn = xp[t * 768 + 512 + tid];
    }
    float acc = bh;
    const uint4* hp = (const uint4*)h16;
    #pragma unroll
    for (int i = 0; i < 32; ++i) {
      uint4 hv = hp[i];
      acc = fdot2f(wreg[i].x, hv.x, acc);
      acc = fdot2f(wreg[i].y, hv.y, acc);
      acc = fdot2f(wreg[i].z, hv.z, acc);
      acc = fdot2f(wreg[i].w, hv.w, acc);
    }
    gh[tid] = acc;
    __syncthreads();
    if (tid < 256) {
      float r  = sigm(xr + gh[tid]);
      float z  = sigm(xz + gh[256 + tid]);
      float n  = tanhf_fast(xn + r * gh[512 + tid]);
      float hn = (1.f - z) * n + z * h32[tid];
      h32[tid] = hn;
      hs[t * 256 + tid] = hn;
      h16[tid] = __builtin_bit_cast(unsigned short, (_Float16)hn);
    }
    __syncthreads();
  }

  if (w < 32) {
    if (tid < 256) {
      float acc = 0.f;
      const float* r1 = intra_w1 + tid * 256;
      #pragma unroll 16
      for (int k = 0; k < 256; k += 4) {
        float4 wv = *(const float4*)(r1 + k);
        float4 hv = *(const float4*)&h32[k];
        acc += hv.x*wv.x + hv.y*wv.y + hv.z*wv.z + hv.w*wv.w;
      }
      ws[OFF_QHH + w * 256 + tid] = fmaxf(acc, 0.f);
    }
  } else {
    float acc = bh;
    const uint4* hp = (const uint4*)h16;
    #pragma unroll
    for (int i = 0; i < 32; ++i) {
      uint4 hv = hp[i];
      acc = fdot2f(wreg[i].x, hv.x, acc);
      acc = fdot2f(wreg[i].y, hv.y, acc);
      acc = fdot2f(wreg[i].z, hv.z, acc);
      acc = fdot2f(wreg[i].w, hv.w, acc);
    }
    ws[OFF_GHL + (w - 32) * 768 + tid] = acc;
  }
}

// ================= K3: candidate final GRU step (16 rows/block, W in LDS) ================
__global__ __launch_bounds__(256) void k_cand(const int* cur_tr, const int* cand_set,
                                              const float* loc_emb, const float* W_ih,
                                              float* ws) {
  __shared__ float Ws[768][17];
  __shared__ float Xs[16][20];     // transposed
  int blk = blockIdx.x, tid = threadIdx.x;
  int r0 = blk * 16;
  int s = r0 >> 7;                 // 128 candidates per s, 16 | 128

  float accA[16], accB[16], accC[16];
  #pragma unroll
  for (int r = 0; r < 16; ++r) { accA[r] = 0.f; accB[r] = 0.f; accC[r] = 0.f; }

  for (int kb = 0; kb < 8; ++kb) {
    for (int i = tid; i < 768 * 4; i += 256) {
      int j = i >> 2, q = (i & 3) * 4;
      float4 w = *(const float4*)&W_ih[j * NEMB + 64 + kb * 16 + q];
      Ws[j][q] = w.x; Ws[j][q+1] = w.y; Ws[j][q+2] = w.z; Ws[j][q+3] = w.w;
    }
    if (tid < 64) {
      int r = tid >> 2, q = (tid & 3) * 4;
      float4 x = *(const float4*)&loc_emb[cand_set[r0 + r] * 128 + kb * 16 + q];
      Xs[q][r] = x.x; Xs[q+1][r] = x.y; Xs[q+2][r] = x.z; Xs[q+3][r] = x.w;
    }
    __syncthreads();
    #pragma unroll
    for (int kk = 0; kk < 16; ++kk) {
      float wa = Ws[tid][kk], wb = Ws[tid + 256][kk], wc = Ws[tid + 512][kk];
      float4 x0 = *(const float4*)&Xs[kk][0];
      float4 x1 = *(const float4*)&Xs[kk][4];
      float4 x2 = *(const float4*)&Xs[kk][8];
      float4 x3 = *(const float4*)&Xs[kk][12];
      float xv[16] = {x0.x,x0.y,x0.z,x0.w, x1.x,x1.y,x1.z,x1.w,
                      x2.x,x2.y,x2.z,x2.w, x3.x,x3.y,x3.z,x3.w};
      #pragma unroll
      for (int r = 0; r < 16; ++r) {
        accA[r] += xv[r] * wa; accB[r] += xv[r] * wb; accC[r] += xv[r] * wc;
      }
    }
    __syncthreads();
  }

  int last = s * 32 + 31;
  int wd = cur_tr[last * 3 + 1], hr = cur_tr[last * 3 + 2];
  const float* wdp = ws + OFF_WDP + wd * 768;
  const float* hrp = ws + OFF_HRP + hr * 768;
  float xbA = ws[OFF_BASE + tid]       + wdp[tid]       + hrp[tid];
  float xbB = ws[OFF_BASE + 256 + tid] + wdp[256 + tid] + hrp[256 + tid];
  float xbC = ws[OFF_BASE + 512 + tid] + wdp[512 + tid] + hrp[512 + tid];
  float ghr = ws[OFF_GHL + s * 768 + tid];
  float ghz = ws[OFF_GHL + s * 768 + 256 + tid];
  float ghn = ws[OFF_GHL + s * 768 + 512 + tid];
  float hp  = ws[OFF_HSC + last * 256 + tid];

  for (int r = 0; r < 16; ++r) {
    float rr = sigm(xbA + accA[r] + ghr);
    float zz = sigm(xbB + accB[r] + ghz);
    float nn = tanhf_fast(xbC + accC[r] + ghn);
    float hn = (1.f - zz) * nn + zz * hp;
    ws[OFF_HC + (r0 + r) * 256 + tid] = hn;
  }
}

// ================= K4/K7 common: OUT[32 rows x 256] = relu(X @ W.T), W in LDS ============
__device__ __forceinline__ void proj_body(const float* in, float* out, const float* W,
                                          int r0, int tid) {
  __shared__ float Ws[256][33];
  __shared__ float Xs[32][36];     // transposed: Xs[k][r]
  int c0 = tid & 63, rg = (tid >> 6) * 8;
  float acc[4][8];
  #pragma unroll
  for (int c = 0; c < 4; ++c)
    #pragma unroll
    for (int r = 0; r < 8; ++r) acc[c][r] = 0.f;

  for (int kb = 0; kb < 8; ++kb) {
    for (int i = tid; i < 256 * 8; i += 256) {
      int j = i >> 3, q = (i & 7) * 4;
      float4 v = *(const float4*)&W[j * 256 + kb * 32 + q];
      Ws[j][q] = v.x; Ws[j][q+1] = v.y; Ws[j][q+2] = v.z; Ws[j][q+3] = v.w;
    }
    {
      int r = tid >> 3, q = (tid & 7) * 4;
      float4 v = *(const float4*)&in[(r0 + r) * 256 + kb * 32 + q];
      Xs[q][r] = v.x; Xs[q+1][r] = v.y; Xs[q+2][r] = v.z; Xs[q+3][r] = v.w;
    }
    __syncthreads();
    #pragma unroll
    for (int kk = 0; kk < 32; ++kk) {
      float w0 = Ws[c0][kk], w1 = Ws[c0 + 64][kk], w2 = Ws[c0 + 128][kk], w3 = Ws[c0 + 192][kk];
      float4 xa = *(const float4*)&Xs[kk][rg];
      float4 xb = *(const float4*)&Xs[kk][rg + 4];
      float xv[8] = {xa.x,xa.y,xa.z,xa.w, xb.x,xb.y,xb.z,xb.w};
      #pragma unroll
      for (int r = 0; r < 8; ++r) {
        acc[0][r] += xv[r] * w0; acc[1][r] += xv[r] * w1;
        acc[2][r] += xv[r] * w2; acc[3][r] += xv[r] * w3;
      }
    }
    __syncthreads();
  }
  #pragma unroll
  for (int c = 0; c < 4; ++c)
    for (int r = 0; r < 8; ++r)
      out[(r0 + rg + r) * 256 + c0 + c * 64] = fmaxf(acc[c][r], 0.f);
}

// blk<64: HSH->KHH | <96: HSC->KHSH | <224: HC->KHC | <352: HC->QHC
__global__ __launch_bounds__(256) void k_proj_intra(const float* intra_w1, const float* intra_w2,
                                                    float* ws) {
  int blk = blockIdx.x, tid = threadIdx.x;
  const float* in; float* out; const float* W; int r0;
  if (blk < 64)       { in = ws + OFF_HSH; out = ws + OFF_KHH;  W = intra_w2; r0 = blk * 32; }
  else if (blk < 96)  { in = ws + OFF_HSC; out = ws + OFF_KHSH; W = intra_w2; r0 = (blk - 64) * 32; }
  else if (blk < 224) { in = ws + OFF_HC;  out = ws + OFF_KHC;  W = intra_w2; r0 = (blk - 96) * 32; }
  else                { in = ws + OFF_HC;  out = ws + OFF_QHC;  W = intra_w1; r0 = (blk - 224) * 32; }
  proj_body(in, out, W, r0, tid);
}

// blk<128: CHID->QH2 (inter_w1) | blk==128: HIST->KH2 (inter_w2)
__global__ __launch_bounds__(256) void k_proj_inter(const float* inter_w1, const float* inter_w2,
                                                    float* ws) {
  int blk = blockIdx.x, tid = threadIdx.x;
  const float* in; float* out; const float* W; int r0;
  if (blk < 128) { in = ws + OFF_CHID; out = ws + OFF_QH2; W = inter_w1; r0 = blk * 32; }
  else           { in = ws + OFF_HIST; out = ws + OFF_KH2; W = inter_w2; r0 = 0; }
  proj_body(in, out, W, r0, tid);
}

// ================= K5: history intra attention -> hist_hidden ============================
__global__ __launch_bounds__(256) void k_hist_attn(const float* intra_out, float* ws) {
  __shared__ __align__(16) float a[64];
  int b = blockIdx.x, tid = threadIdx.x;
  int wv = tid >> 6, lane = tid & 63;
  const float* qh = ws + OFF_QHH + b * 256;
  const float* kh = ws + OFF_KHH + b * 64 * 256;
  const float* hs = ws + OFF_HSH + b * 64 * 256;

  float4 q4  = *(const float4*)&qh[lane * 4];
  float4 io4 = *(const float4*)&intra_out[lane * 4];
  for (int t = wv; t < 64; t += 4) {
    float4 k4 = *(const float4*)&kh[t * 256 + lane * 4];
    float p = tanhf_fast(q4.x + k4.x) * io4.x + tanhf_fast(q4.y + k4.y) * io4.y +
              tanhf_fast(q4.z + k4.z) * io4.z + tanhf_fast(q4.w + k4.w) * io4.w;
    #pragma unroll
    for (int off = 32; off; off >>= 1) p += __shfl_down(p, off);
    if (lane == 0) a[t] = p;
  }
  __syncthreads();
  if (tid < 64) {
    float v = a[tid];
    float m = v;
    #pragma unroll
    for (int off = 32; off; off >>= 1) m = fmaxf(m, __shfl_xor(m, off));
    float e = __expf(v - m);
    float ssum = e;
    #pragma unroll
    for (int off = 32; off; off >>= 1) ssum += __shfl_xor(ssum, off);
    a[tid] = e / ssum;
  }
  __syncthreads();
  float acc = 0.f;
  for (int t = 0; t < 64; ++t) acc += a[t] * hs[t * 256 + tid];
  ws[OFF_HIST + b * 256 + tid] = acc;
}

// ================= K6: candidate intra attention (transposed; 4 cands/block) =============
// 1024 blocks x 256 thr. s = blk>>5, cands = (blk&31)*4 .. +3, wave w -> cand w.
// Lane t<33 owns score row t (t<32: shared K, t==32: own K); ONE softmax shuffle pass.
__global__ __launch_bounds__(256) void k_cand_attn(const float* intra_out, float* ws) {
  __shared__ float Ks[32][260];
  __shared__ float Kc[4][260];
  __shared__ float Qs[4][260];
  __shared__ float Io[260];
  __shared__ float aw[4][36];
  int blk = blockIdx.x, tid = threadIdx.x;
  int s = blk >> 5;
  int bId0 = s * 128 + (blk & 31) * 4;
  int w = tid >> 6, lane = tid & 63;

  for (int i = tid; i < 32 * 256; i += 256) {
    int t = i >> 8, d = i & 255;
    Ks[t][d] = ws[OFF_KHSH + (s * 32 + t) * 256 + d];
  }
  for (int i = tid; i < 4 * 256; i += 256) {
    int c = i >> 8, d = i & 255;
    Kc[c][d] = ws[OFF_KHC + (bId0 + c) * 256 + d];
    Qs[c][d] = ws[OFF_QHC + (bId0 + c) * 256 + d];
  }
  Io[tid] = intra_out[tid];
  __syncthreads();

  const float* krow = (lane < 32) ? &Ks[lane][0] : &Kc[w][0];
  float p = 0.f;
  for (int d = 0; d < 256; d += 4) {
    float4 k4 = *(const float4*)&krow[d];
    float4 q4 = *(const float4*)&Qs[w][d];
    float4 i4 = *(const float4*)&Io[d];
    p += tanhf_fast(q4.x + k4.x) * i4.x + tanhf_fast(q4.y + k4.y) * i4.y +
         tanhf_fast(q4.z + k4.z) * i4.z + tanhf_fast(q4.w + k4.w) * i4.w;
  }
  if (lane >= 33) p = -1e30f;
  float m = p;
  #pragma unroll
  for (int off = 32; off; off >>= 1) m = fmaxf(m, __shfl_xor(m, off));
  float e = __expf(p - m);                 // lanes>=33 -> 0
  float ssum = e;
  #pragma unroll
  for (int off = 32; off; off >>= 1) ssum += __shfl_xor(ssum, off);
  float wt = e / ssum;
  if (lane < 33) aw[w][lane] = wt;
  __syncthreads();

  const float* hsc = ws + OFF_HSC + s * 32 * 256;
  const float* hc  = ws + OFF_HC + (bId0 + w) * 256;
  float ax = 0.f, ay = 0.f, az = 0.f, az2 = 0.f;
  for (int t = 0; t < 32; ++t) {
    float wt2 = aw[w][t];
    float4 hv = *(const float4*)&hsc[t * 256 + lane * 4];
    ax += wt2 * hv.x; ay += wt2 * hv.y; az += wt2 * hv.z; az2 += wt2 * hv.w;
  }
  {
    float wt2 = aw[w][32];
    float4 hv = *(const float4*)&hc[lane * 4];
    ax += wt2 * hv.x; ay += wt2 * hv.y; az += wt2 * hv.z; az2 += wt2 * hv.w;
  }
  float4 o; o.x = ax; o.y = ay; o.z = az; o.w = az2;
  *(float4*)&ws[OFF_CHID + (bId0 + w) * 256 + lane * 4] = o;
}

// ================= K8: inter attention (transposed; 4 cands/block) =======================
// 1024 blocks x 256 thr, wave per cand; lane t<32 owns hist row t.
__global__ __launch_bounds__(256) void k_inter_attn(const float* inter_out, const float* score_w,
                                                    float* ws, float* d_out) {
  __shared__ float Ks[32][260];
  __shared__ float Qs[4][260];
  __shared__ float Io[260];
  __shared__ float aw[4][36];
  int blk = blockIdx.x, tid = threadIdx.x;
  int bId0 = blk * 4;
  int w = tid >> 6, lane = tid & 63;

  for (int i = tid; i < 32 * 256; i += 256) {
    int t = i >> 8, d = i & 255;
    Ks[t][d] = ws[OFF_KH2 + t * 256 + d];
  }
  for (int i = tid; i < 4 * 256; i += 256) {
    int c = i >> 8, d = i & 255;
    Qs[c][d] = ws[OFF_QH2 + (bId0 + c) * 256 + d];
  }
  Io[tid] = inter_out[tid];
  __syncthreads();

  const float* krow = (lane < 32) ? &Ks[lane][0] : &Ks[0][0];
  float p = 0.f;
  for (int d = 0; d < 256; d += 4) {
    float4 k4 = *(const float4*)&krow[d];
    float4 q4 = *(const float4*)&Qs[w][d];
    float4 i4 = *(const float4*)&Io[d];
    p += tanhf_fast(q4.x + k4.x) * i4.x + tanhf_fast(q4.y + k4.y) * i4.y +
         tanhf_fast(q4.z + k4.z) * i4.z + tanhf_fast(q4.w + k4.w) * i4.w;
  }
  if (lane >= 32) p = -1e30f;
  float m = p;
  #pragma unroll
  for (int off = 32; off; off >>= 1) m = fmaxf(m, __shfl_xor(m, off));
  float e = __expf(p - m);
  float ssum = e;
  #pragma unroll
  for (int off = 32; off; off >>= 1) ssum += __shfl_xor(ssum, off);
  float wt = e / ssum;
  if (lane < 32) aw[w][lane] = wt;
  __syncthreads();

  const float* hist = ws + OFF_HIST;
  float ax = 0.f, ay = 0.f, az = 0.f, az2 = 0.f;
  for (int t = 0; t < 32; ++t) {
    float wt2 = aw[w][t];
    float4 hv = *(const float4*)&hist[t * 256 + lane * 4];
    ax += wt2 * hv.x; ay += wt2 * hv.y; az += wt2 * hv.z; az2 += wt2 * hv.w;
  }
  float4 o; o.x = ax; o.y = ay; o.z = az; o.w = az2;
  *(float4*)&d_out[4096 + (bId0 + w) * 256 + lane * 4] = o;
  float4 sw = *(const float4*)&score_w[lane * 4];
  float sc = ax*sw.x + ay*sw.y + az*sw.z + az2*sw.w;
  #pragma unroll
  for (int off = 32; off; off >>= 1) sc += __shfl_xor(sc, off);
  if (lane == 0) ws[OFF_SC + bId0 + w] = sc;
}

// ================= K9: probs = softmax over C=128 per s ==================================
__global__ __launch_bounds__(64) void k_probs(const float* ws, float* d_out) {
  int s = blockIdx.x, lane = threadIdx.x;
  float v0 = ws[OFF_SC + s * 128 + lane];
  float v1 = ws[OFF_SC + s * 128 + 64 + lane];
  float m = fmaxf(v0, v1);
  #pragma unroll
  for (int off = 32; off; off >>= 1) m = fmaxf(m, __shfl_xor(m, off));
  float e0 = __expf(v0 - m), e1 = __expf(v1 - m);
  float ssum = e0 + e1;
  #pragma unroll
  for (int off = 32; off; off >>= 1) ssum += __shfl_xor(ssum, off);
  float inv = 1.f / ssum;
  d_out[s * 128 + lane] = e0 * inv;
  d_out[s * 128 + 64 + lane] = e1 * inv;
}

// ======================= launch =========================================================
extern "C" void kernel_launch(void* const* d_in, const int* in_sizes, int n_in,
                              void* d_out, int out_size, void* d_ws, size_t ws_size,
                              hipStream_t stream) {
  const int*   uid      = (const int*)  d_in[0];
  const int*   cur_tr   = (const int*)  d_in[1];
  const int*   hist_tr  = (const int*)  d_in[2];
  const int*   cand_set = (const int*)  d_in[3];
  const float* uid_emb  = (const float*)d_in[4];
  const float* loc_emb  = (const float*)d_in[5];
  const float* wde      = (const float*)d_in[6];
  const float* hre      = (const float*)d_in[7];
  const float* W_ih     = (const float*)d_in[8];
  const float* W_hh     = (const float*)d_in[9];
  const float* b_ih     = (const float*)d_in[10];
  const float* b_hh     = (const float*)d_in[11];
  const float* intra_w1 = (const float*)d_in[12];
  const float* intra_w2 = (const float*)d_in[13];
  const float* intra_out= (const float*)d_in[14];
  const float* inter_w1 = (const float*)d_in[15];
  const float* inter_w2 = (const float*)d_in[16];
  const float* inter_out= (const float*)d_in[17];
  const float* score_w  = (const float*)d_in[18];
  float* ws  = (float*)d_ws;
  float* out = (float*)d_out;

  hipLaunchKernelGGL(k_prep,       dim3(128),  dim3(256), 0, stream, uid, uid_emb, wde, hre, W_ih, b_ih, W_hh, ws);
  hipLaunchKernelGGL(k_xproj,      dim3(192),  dim3(256), 0, stream, cur_tr, hist_tr, loc_emb, W_ih, ws);
  hipLaunchKernelGGL(k_gru,        dim3(64),   dim3(768), 0, stream, b_hh, intra_w1, ws);
  hipLaunchKernelGGL(k_cand,       dim3(256),  dim3(256), 0, stream, cur_tr, cand_set, loc_emb, W_ih, ws);
  hipLaunchKernelGGL(k_proj_intra, dim3(352),  dim3(256), 0, stream, intra_w1, intra_w2, ws);
  hipLaunchKernelGGL(k_hist_attn,  dim3(32),   dim3(256), 0, stream, intra_out, ws);
  hipLaunchKernelGGL(k_cand_attn,  dim3(1024), dim3(256), 0, stream, intra_out, ws);
  hipLaunchKernelGGL(k_proj_inter, dim3(129),  dim3(256), 0, stream, inter_w1, inter_w2, ws);
  hipLaunchKernelGGL(k_inter_attn, dim3(1024), dim3(256), 0, stream, inter_out, score_w, ws, out);
  hipLaunchKernelGGL(k_probs,      dim3(32),   dim3(64),  0, stream, ws, out);
}

// Round 10
// 426.665 us; speedup vs baseline: 1.2573x; 1.0325x over previous
//
#include <hip/hip_runtime.h>
#include <math.h>

// ---------------- problem constants ----------------
#define NHID   256
#define NEMB   224

// ---------------- workspace layout (float indices) ----------------
constexpr int OFF_BASE = 0;                          // 768   (b_ih + uid proj)
constexpr int OFF_WDP  = 768;                        // 7*768
constexpr int OFF_HRP  = OFF_WDP + 7*768;            // 24*768
constexpr int OFF_XPH  = OFF_HRP + 24*768;           // 32*64*768
constexpr int OFF_XPC  = OFF_XPH + 32*64*768;        // 32*32*768
constexpr int OFF_HSH  = OFF_XPC + 32*32*768;        // 32*64*256
constexpr int OFF_HSC  = OFF_HSH + 32*64*256;        // 32*32*256
constexpr int OFF_GHL  = OFF_HSC + 32*32*256;        // 32*768
constexpr int OFF_QHH  = OFF_GHL + 32*768;           // 32*256
constexpr int OFF_HC   = OFF_QHH + 32*256;           // 4096*256
constexpr int OFF_KHH  = OFF_HC  + 4096*256;         // 32*64*256
constexpr int OFF_KHSH = OFF_KHH + 32*64*256;        // 32*32*256
constexpr int OFF_KHC  = OFF_KHSH+ 32*32*256;        // 4096*256
constexpr int OFF_QHC  = OFF_KHC + 4096*256;         // 4096*256
constexpr int OFF_HIST = OFF_QHC + 4096*256;         // 32*256
constexpr int OFF_CHID = OFF_HIST+ 32*256;           // 4096*256
constexpr int OFF_QH2  = OFF_CHID+ 4096*256;         // 4096*256 (unused now; layout kept)
constexpr int OFF_KH2  = OFF_QH2 + 4096*256;         // 32*256
constexpr int OFF_SC   = OFF_KH2 + 32*256;           // 4096 scores
// W_hh packed fp16 (24576 uint4 = 393KB) ALIASES the KHH region: written by
// k_prep (pack blocks), consumed only by k_gru, then k_proj_intra overwrites KHH.
constexpr int OFF_W16  = OFF_KHH;                    // as uint32 index

__device__ __forceinline__ float sigm(float x) { return 1.0f / (1.0f + __expf(-x)); }
// fast tanh: exact at saturation, ~1e-7 rel err (validated R7: absmax unchanged)
__device__ __forceinline__ float tanhf_fast(float x) {
  return 1.f - 2.f / (__expf(2.f * x) + 1.f);
}

typedef _Float16 half2_t __attribute__((ext_vector_type(2)));

__device__ __forceinline__ float fdot2f(unsigned int a, unsigned int b, float c) {
#if __has_builtin(__builtin_amdgcn_fdot2)
  return __builtin_amdgcn_fdot2(__builtin_bit_cast(half2_t, a),
                                __builtin_bit_cast(half2_t, b), c, false);
#else
  half2_t x = __builtin_bit_cast(half2_t, a);
  half2_t y = __builtin_bit_cast(half2_t, b);
  return c + (float)x[0] * (float)y[0] + (float)x[1] * (float)y[1];
#endif
}

__device__ __forceinline__ unsigned int packh(float a, float b) {
  unsigned short lo = __builtin_bit_cast(unsigned short, (_Float16)a);
  unsigned short hi = __builtin_bit_cast(unsigned short, (_Float16)b);
  return (unsigned int)lo | ((unsigned int)hi << 16);
}

// ================= K0: prep tables + W_hh fp16 pack (merged; validated) ==================
__global__ __launch_bounds__(256) void k_prep(const int* uid, const float* uid_emb,
                                              const float* wde, const float* hre,
                                              const float* W_ih, const float* b_ih,
                                              const float* W_hh, float* ws) {
  __shared__ __align__(16) float ev[64];
  int blk = blockIdx.x, tid = threadIdx.x;
  if (blk >= 32) {                                 // pack W_hh
    int idx = (blk - 32) * 256 + tid;              // 0..24575
    int i4 = idx & 31, j = idx >> 5;
    const float4* p = (const float4*)(W_hh + j * 256 + i4 * 8);
    float4 a = p[0], b = p[1];
    uint4 o;
    o.x = packh(a.x, a.y); o.y = packh(a.z, a.w);
    o.z = packh(b.x, b.y); o.w = packh(b.z, b.w);
    ((uint4*)((unsigned int*)ws + OFF_W16))[i4 * 768 + j] = o;
    return;
  }
  if (blk == 0) {
    if (tid < 64) ev[tid] = uid_emb[uid[0] * 64 + tid];
    __syncthreads();
    #pragma unroll
    for (int jj = 0; jj < 3; ++jj) {
      int j = tid + jj * 256;
      float acc = b_ih[j];
      const float* wr = W_ih + j * NEMB;
      #pragma unroll
      for (int k = 0; k < 64; k += 4) {
        float4 w = *(const float4*)(wr + k);
        acc += ev[k]*w.x + ev[k+1]*w.y + ev[k+2]*w.z + ev[k+3]*w.w;
      }
      ws[OFF_BASE + j] = acc;
    }
  } else if (blk < 8) {
    int wd = blk - 1;
    if (tid < 16) ev[tid] = wde[wd * 16 + tid];
    __syncthreads();
    #pragma unroll
    for (int jj = 0; jj < 3; ++jj) {
      int j = tid + jj * 256;
      float acc = 0.f;
      const float* wr = W_ih + j * NEMB + 192;
      #pragma unroll
      for (int k = 0; k < 16; k += 4) {
        float4 w = *(const float4*)(wr + k);
        acc += ev[k]*w.x + ev[k+1]*w.y + ev[k+2]*w.z + ev[k+3]*w.w;
      }
      ws[OFF_WDP + wd * 768 + j] = acc;
    }
  } else {
    int hr = blk - 8;
    if (tid < 16) ev[tid] = hre[hr * 16 + tid];
    __syncthreads();
    #pragma unroll
    for (int jj = 0; jj < 3; ++jj) {
      int j = tid + jj * 256;
      float acc = 0.f;
      const float* wr = W_ih + j * NEMB + 208;
      #pragma unroll
      for (int k = 0; k < 16; k += 4) {
        float4 w = *(const float4*)(wr + k);
        acc += ev[k]*w.x + ev[k+1]*w.y + ev[k+2]*w.z + ev[k+3]*w.w;
      }
      ws[OFF_HRP + hr * 768 + j] = acc;
    }
  }
}

// ================= K1: x_proj rows (hist 2048 + curr 1024); 16 rows/block, W in LDS ======
__global__ __launch_bounds__(256) void k_xproj(const int* cur_tr, const int* hist_tr,
                                               const float* loc_emb, const float* W_ih,
                                               float* ws) {
  __shared__ float Ws[768][17];
  __shared__ float Xs[16][20];     // transposed: Xs[k][r]
  __shared__ int s_wd[16], s_hr[16], s_loc[16];
  int blk = blockIdx.x, tid = threadIdx.x;
  int r0 = blk * 16;

  if (tid < 16) {
    int row = r0 + tid;
    const int* tr; int idx;
    if (row < 2048) { tr = hist_tr; idx = row; } else { tr = cur_tr; idx = row - 2048; }
    s_loc[tid] = tr[idx * 3];
    s_wd[tid]  = tr[idx * 3 + 1];
    s_hr[tid]  = tr[idx * 3 + 2];
  }
  __syncthreads();

  float accA[16], accB[16], accC[16];
  #pragma unroll
  for (int r = 0; r < 16; ++r) { accA[r] = 0.f; accB[r] = 0.f; accC[r] = 0.f; }

  for (int kb = 0; kb < 8; ++kb) {
    for (int i = tid; i < 768 * 4; i += 256) {
      int j = i >> 2, q = (i & 3) * 4;
      float4 w = *(const float4*)&W_ih[j * NEMB + 64 + kb * 16 + q];
      Ws[j][q] = w.x; Ws[j][q+1] = w.y; Ws[j][q+2] = w.z; Ws[j][q+3] = w.w;
    }
    if (tid < 64) {
      int r = tid >> 2, q = (tid & 3) * 4;
      float4 x = *(const float4*)&loc_emb[s_loc[r] * 128 + kb * 16 + q];
      Xs[q][r] = x.x; Xs[q+1][r] = x.y; Xs[q+2][r] = x.z; Xs[q+3][r] = x.w;
    }
    __syncthreads();
    #pragma unroll
    for (int kk = 0; kk < 16; ++kk) {
      float wa = Ws[tid][kk], wb = Ws[tid + 256][kk], wc = Ws[tid + 512][kk];
      float4 x0 = *(const float4*)&Xs[kk][0];
      float4 x1 = *(const float4*)&Xs[kk][4];
      float4 x2 = *(const float4*)&Xs[kk][8];
      float4 x3 = *(const float4*)&Xs[kk][12];
      float xv[16] = {x0.x,x0.y,x0.z,x0.w, x1.x,x1.y,x1.z,x1.w,
                      x2.x,x2.y,x2.z,x2.w, x3.x,x3.y,x3.z,x3.w};
      #pragma unroll
      for (int r = 0; r < 16; ++r) {
        accA[r] += xv[r] * wa; accB[r] += xv[r] * wb; accC[r] += xv[r] * wc;
      }
    }
    __syncthreads();
  }

  float bA = ws[OFF_BASE + tid], bB = ws[OFF_BASE + 256 + tid], bC = ws[OFF_BASE + 512 + tid];
  for (int r = 0; r < 16; ++r) {
    int row = r0 + r;
    float* outp = (row < 2048) ? (ws + OFF_XPH + row * 768)
                               : (ws + OFF_XPC + (row - 2048) * 768);
    const float* wdp = ws + OFF_WDP + s_wd[r] * 768;
    const float* hrp = ws + OFF_HRP + s_hr[r] * 768;
    outp[tid]       = accA[r] + bA + wdp[tid]       + hrp[tid];
    outp[256 + tid] = accB[r] + bB + wdp[256 + tid] + hrp[256 + tid];
    outp[512 + tid] = accC[r] + bC + wdp[512 + tid] + hrp[512 + tid];
  }
}

// ================= K2: GRU scans — R6/R9 structure (measured 89 µs; VGPR 80) =============
__global__ __launch_bounds__(768) void k_gru(const float* b_hh, const float* intra_w1,
                                             float* ws) {
  __shared__ __align__(16) float gh[768];
  __shared__ __align__(16) float h32[256];
  __shared__ __align__(16) unsigned short h16[256];
  int w = blockIdx.x, tid = threadIdx.x;
  int T; const float* xp; float* hs;
  if (w < 32) { T = 64; xp = ws + OFF_XPH + w * 64 * 768; hs = ws + OFF_HSH + w * 64 * 256; }
  else        { T = 32; int b = w - 32; xp = ws + OFF_XPC + b * 32 * 768; hs = ws + OFF_HSC + b * 32 * 256; }

  uint4 wreg[32];
  {
    const uint4* wp = (const uint4*)((const unsigned int*)ws + OFF_W16) + tid;
    #pragma unroll
    for (int i = 0; i < 32; ++i) wreg[i] = wp[i * 768];
  }
  float bh = b_hh[tid];
  if (tid < 256) { h32[tid] = 0.f; h16[tid] = 0; }
  __syncthreads();

  for (int t = 0; t < T; ++t) {
    float xr, xz, xn;
    if (tid < 256) {
      xr = xp[t * 768 + tid];
      xz = xp[t * 768 + 256 + tid];
      xn = xp[t * 768 + 512 + tid];
    }
    float acc = bh;
    const uint4* hp = (const uint4*)h16;
    #pragma unroll
    for (int i = 0; i < 32; ++i) {
      uint4 hv = hp[i];
      acc = fdot2f(wreg[i].x, hv.x, acc);
      acc = fdot2f(wreg[i].y, hv.y, acc);
      acc = fdot2f(wreg[i].z, hv.z, acc);
      acc = fdot2f(wreg[i].w, hv.w, acc);
    }
    gh[tid] = acc;
    __syncthreads();
    if (tid < 256) {
      float r  = sigm(xr + gh[tid]);
      float z  = sigm(xz + gh[256 + tid]);
      float n  = tanhf_fast(xn + r * gh[512 + tid]);
      float hn = (1.f - z) * n + z * h32[tid];
      h32[tid] = hn;
      hs[t * 256 + tid] = hn;
      h16[tid] = __builtin_bit_cast(unsigned short, (_Float16)hn);
    }
    __syncthreads();
  }

  if (w < 32) {
    if (tid < 256) {
      float acc = 0.f;
      const float* r1 = intra_w1 + tid * 256;
      #pragma unroll 16
      for (int k = 0; k < 256; k += 4) {
        float4 wv = *(const float4*)(r1 + k);
        float4 hv = *(const float4*)&h32[k];
        acc += hv.x*wv.x + hv.y*wv.y + hv.z*wv.z + hv.w*wv.w;
      }
      ws[OFF_QHH + w * 256 + tid] = fmaxf(acc, 0.f);
    }
  } else {
    float acc = bh;
    const uint4* hp = (const uint4*)h16;
    #pragma unroll
    for (int i = 0; i < 32; ++i) {
      uint4 hv = hp[i];
      acc = fdot2f(wreg[i].x, hv.x, acc);
      acc = fdot2f(wreg[i].y, hv.y, acc);
      acc = fdot2f(wreg[i].z, hv.z, acc);
      acc = fdot2f(wreg[i].w, hv.w, acc);
    }
    ws[OFF_GHL + (w - 32) * 768 + tid] = acc;
  }
}

// ================= K3: candidate final GRU step (16 rows/block, W in LDS) ================
__global__ __launch_bounds__(256) void k_cand(const int* cur_tr, const int* cand_set,
                                              const float* loc_emb, const float* W_ih,
                                              float* ws) {
  __shared__ float Ws[768][17];
  __shared__ float Xs[16][20];     // transposed
  int blk = blockIdx.x, tid = threadIdx.x;
  int r0 = blk * 16;
  int s = r0 >> 7;                 // 128 candidates per s, 16 | 128

  float accA[16], accB[16], accC[16];
  #pragma unroll
  for (int r = 0; r < 16; ++r) { accA[r] = 0.f; accB[r] = 0.f; accC[r] = 0.f; }

  for (int kb = 0; kb < 8; ++kb) {
    for (int i = tid; i < 768 * 4; i += 256) {
      int j = i >> 2, q = (i & 3) * 4;
      float4 w = *(const float4*)&W_ih[j * NEMB + 64 + kb * 16 + q];
      Ws[j][q] = w.x; Ws[j][q+1] = w.y; Ws[j][q+2] = w.z; Ws[j][q+3] = w.w;
    }
    if (tid < 64) {
      int r = tid >> 2, q = (tid & 3) * 4;
      float4 x = *(const float4*)&loc_emb[cand_set[r0 + r] * 128 + kb * 16 + q];
      Xs[q][r] = x.x; Xs[q+1][r] = x.y; Xs[q+2][r] = x.z; Xs[q+3][r] = x.w;
    }
    __syncthreads();
    #pragma unroll
    for (int kk = 0; kk < 16; ++kk) {
      float wa = Ws[tid][kk], wb = Ws[tid + 256][kk], wc = Ws[tid + 512][kk];
      float4 x0 = *(const float4*)&Xs[kk][0];
      float4 x1 = *(const float4*)&Xs[kk][4];
      float4 x2 = *(const float4*)&Xs[kk][8];
      float4 x3 = *(const float4*)&Xs[kk][12];
      float xv[16] = {x0.x,x0.y,x0.z,x0.w, x1.x,x1.y,x1.z,x1.w,
                      x2.x,x2.y,x2.z,x2.w, x3.x,x3.y,x3.z,x3.w};
      #pragma unroll
      for (int r = 0; r < 16; ++r) {
        accA[r] += xv[r] * wa; accB[r] += xv[r] * wb; accC[r] += xv[r] * wc;
      }
    }
    __syncthreads();
  }

  int last = s * 32 + 31;
  int wd = cur_tr[last * 3 + 1], hr = cur_tr[last * 3 + 2];
  const float* wdp = ws + OFF_WDP + wd * 768;
  const float* hrp = ws + OFF_HRP + hr * 768;
  float xbA = ws[OFF_BASE + tid]       + wdp[tid]       + hrp[tid];
  float xbB = ws[OFF_BASE + 256 + tid] + wdp[256 + tid] + hrp[256 + tid];
  float xbC = ws[OFF_BASE + 512 + tid] + wdp[512 + tid] + hrp[512 + tid];
  float ghr = ws[OFF_GHL + s * 768 + tid];
  float ghz = ws[OFF_GHL + s * 768 + 256 + tid];
  float ghn = ws[OFF_GHL + s * 768 + 512 + tid];
  float hp  = ws[OFF_HSC + last * 256 + tid];

  for (int r = 0; r < 16; ++r) {
    float rr = sigm(xbA + accA[r] + ghr);
    float zz = sigm(xbB + accB[r] + ghz);
    float nn = tanhf_fast(xbC + accC[r] + ghn);
    float hn = (1.f - zz) * nn + zz * hp;
    ws[OFF_HC + (r0 + r) * 256 + tid] = hn;
  }
}

// ============ K4: proj (fp16-packed inner): OUT[32 x 256] = relu(X @ W.T) ================
// fdot2 halves VALU insts + LDS traffic vs fp32 fmac. Accumulation stays fp32.
__device__ __forceinline__ void proj_body16(const float* in, float* out, const float* W,
                                            int r0, int tid) {
  __shared__ unsigned int WsH[256][21];   // [col j][k2] pairs along k; 21 odd -> no bank alias
  __shared__ unsigned int XsH[16][40];    // [k2][row r] pairs along k; row 160B (16B-aligned)
  int c0 = tid & 63, rg = (tid >> 6) * 8;
  float acc[4][8];
  #pragma unroll
  for (int c = 0; c < 4; ++c)
    #pragma unroll
    for (int r = 0; r < 8; ++r) acc[c][r] = 0.f;

  for (int kb = 0; kb < 8; ++kb) {
    for (int i = tid; i < 256 * 8; i += 256) {
      int j = i >> 3, q = i & 7;
      float4 v = *(const float4*)&W[j * 256 + kb * 32 + q * 4];
      WsH[j][q * 2]     = packh(v.x, v.y);
      WsH[j][q * 2 + 1] = packh(v.z, v.w);
    }
    {
      int r = tid >> 3, q = tid & 7;
      float4 v = *(const float4*)&in[(r0 + r) * 256 + kb * 32 + q * 4];
      XsH[q * 2][r]     = packh(v.x, v.y);
      XsH[q * 2 + 1][r] = packh(v.z, v.w);
    }
    __syncthreads();
    #pragma unroll
    for (int kk = 0; kk < 16; ++kk) {
      unsigned int w0 = WsH[c0][kk],       w1 = WsH[c0 + 64][kk];
      unsigned int w2 = WsH[c0 + 128][kk], w3 = WsH[c0 + 192][kk];
      uint4 xa = *(const uint4*)&XsH[kk][rg];
      uint4 xb = *(const uint4*)&XsH[kk][rg + 4];
      unsigned int xv[8] = {xa.x, xa.y, xa.z, xa.w, xb.x, xb.y, xb.z, xb.w};
      #pragma unroll
      for (int r = 0; r < 8; ++r) {
        acc[0][r] = fdot2f(w0, xv[r], acc[0][r]);
        acc[1][r] = fdot2f(w1, xv[r], acc[1][r]);
        acc[2][r] = fdot2f(w2, xv[r], acc[2][r]);
        acc[3][r] = fdot2f(w3, xv[r], acc[3][r]);
      }
    }
    __syncthreads();
  }
  #pragma unroll
  for (int c = 0; c < 4; ++c)
    for (int r = 0; r < 8; ++r)
      out[(r0 + rg + r) * 256 + c0 + c * 64] = fmaxf(acc[c][r], 0.f);
}

// blk<64: HSH->KHH | <96: HSC->KHSH | <224: HC->KHC | <352: HC->QHC
__global__ __launch_bounds__(256) void k_proj_intra(const float* intra_w1, const float* intra_w2,
                                                    float* ws) {
  int blk = blockIdx.x, tid = threadIdx.x;
  const float* in; float* out; const float* W; int r0;
  if (blk < 64)       { in = ws + OFF_HSH; out = ws + OFF_KHH;  W = intra_w2; r0 = blk * 32; }
  else if (blk < 96)  { in = ws + OFF_HSC; out = ws + OFF_KHSH; W = intra_w2; r0 = (blk - 64) * 32; }
  else if (blk < 224) { in = ws + OFF_HC;  out = ws + OFF_KHC;  W = intra_w2; r0 = (blk - 96) * 32; }
  else                { in = ws + OFF_HC;  out = ws + OFF_QHC;  W = intra_w1; r0 = (blk - 224) * 32; }
  proj_body16(in, out, W, r0, tid);
}

// ================= K5: history intra attention -> hist_hidden (+ fused KH2 proj) =========
__global__ __launch_bounds__(256) void k_hist_attn(const float* intra_out, const float* inter_w2,
                                                   float* ws) {
  __shared__ __align__(16) float a[64];
  __shared__ __align__(16) float hrow[260];
  int b = blockIdx.x, tid = threadIdx.x;
  int wv = tid >> 6, lane = tid & 63;
  const float* qh = ws + OFF_QHH + b * 256;
  const float* kh = ws + OFF_KHH + b * 64 * 256;
  const float* hs = ws + OFF_HSH + b * 64 * 256;

  float4 q4  = *(const float4*)&qh[lane * 4];
  float4 io4 = *(const float4*)&intra_out[lane * 4];
  for (int t = wv; t < 64; t += 4) {
    float4 k4 = *(const float4*)&kh[t * 256 + lane * 4];
    float p = tanhf_fast(q4.x + k4.x) * io4.x + tanhf_fast(q4.y + k4.y) * io4.y +
              tanhf_fast(q4.z + k4.z) * io4.z + tanhf_fast(q4.w + k4.w) * io4.w;
    #pragma unroll
    for (int off = 32; off; off >>= 1) p += __shfl_down(p, off);
    if (lane == 0) a[t] = p;
  }
  __syncthreads();
  if (tid < 64) {
    float v = a[tid];
    float m = v;
    #pragma unroll
    for (int off = 32; off; off >>= 1) m = fmaxf(m, __shfl_xor(m, off));
    float e = __expf(v - m);
    float ssum = e;
    #pragma unroll
    for (int off = 32; off; off >>= 1) ssum += __shfl_xor(ssum, off);
    a[tid] = e / ssum;
  }
  __syncthreads();
  float acc = 0.f;
  for (int t = 0; t < 64; ++t) acc += a[t] * hs[t * 256 + tid];
  ws[OFF_HIST + b * 256 + tid] = acc;
  hrow[tid] = acc;
  __syncthreads();
  // KH2 row b: kh2[j] = relu(sum_k HIST[b][k] * inter_w2[j][k])
  float acck = 0.f;
  const float* w2r = inter_w2 + tid * 256;
  #pragma unroll 8
  for (int k = 0; k < 256; k += 4) {
    float4 wv2 = *(const float4*)(w2r + k);
    float4 hv  = *(const float4*)&hrow[k];
    acck += hv.x*wv2.x + hv.y*wv2.y + hv.z*wv2.z + hv.w*wv2.w;
  }
  ws[OFF_KH2 + b * 256 + tid] = fmaxf(acck, 0.f);
}

// ================= K6: candidate intra attention (transposed; 4 cands/block) =============
__global__ __launch_bounds__(256) void k_cand_attn(const float* intra_out, float* ws) {
  __shared__ float Ks[32][260];
  __shared__ float Kc[4][260];
  __shared__ float Qs[4][260];
  __shared__ float Io[260];
  __shared__ float aw[4][36];
  int blk = blockIdx.x, tid = threadIdx.x;
  int s = blk >> 5;
  int bId0 = s * 128 + (blk & 31) * 4;
  int w = tid >> 6, lane = tid & 63;

  for (int i = tid; i < 32 * 256; i += 256) {
    int t = i >> 8, d = i & 255;
    Ks[t][d] = ws[OFF_KHSH + (s * 32 + t) * 256 + d];
  }
  for (int i = tid; i < 4 * 256; i += 256) {
    int c = i >> 8, d = i & 255;
    Kc[c][d] = ws[OFF_KHC + (bId0 + c) * 256 + d];
    Qs[c][d] = ws[OFF_QHC + (bId0 + c) * 256 + d];
  }
  Io[tid] = intra_out[tid];
  __syncthreads();

  const float* krow = (lane < 32) ? &Ks[lane][0] : &Kc[w][0];
  float p = 0.f;
  for (int d = 0; d < 256; d += 4) {
    float4 k4 = *(const float4*)&krow[d];
    float4 q4 = *(const float4*)&Qs[w][d];
    float4 i4 = *(const float4*)&Io[d];
    p += tanhf_fast(q4.x + k4.x) * i4.x + tanhf_fast(q4.y + k4.y) * i4.y +
         tanhf_fast(q4.z + k4.z) * i4.z + tanhf_fast(q4.w + k4.w) * i4.w;
  }
  if (lane >= 33) p = -1e30f;
  float m = p;
  #pragma unroll
  for (int off = 32; off; off >>= 1) m = fmaxf(m, __shfl_xor(m, off));
  float e = __expf(p - m);                 // lanes>=33 -> 0
  float ssum = e;
  #pragma unroll
  for (int off = 32; off; off >>= 1) ssum += __shfl_xor(ssum, off);
  float wt = e / ssum;
  if (lane < 33) aw[w][lane] = wt;
  __syncthreads();

  const float* hsc = ws + OFF_HSC + s * 32 * 256;
  const float* hc  = ws + OFF_HC + (bId0 + w) * 256;
  float ax = 0.f, ay = 0.f, az = 0.f, az2 = 0.f;
  for (int t = 0; t < 32; ++t) {
    float wt2 = aw[w][t];
    float4 hv = *(const float4*)&hsc[t * 256 + lane * 4];
    ax += wt2 * hv.x; ay += wt2 * hv.y; az += wt2 * hv.z; az2 += wt2 * hv.w;
  }
  {
    float wt2 = aw[w][32];
    float4 hv = *(const float4*)&hc[lane * 4];
    ax += wt2 * hv.x; ay += wt2 * hv.y; az += wt2 * hv.z; az2 += wt2 * hv.w;
  }
  float4 o; o.x = ax; o.y = ay; o.z = az; o.w = az2;
  *(float4*)&ws[OFF_CHID + (bId0 + w) * 256 + lane * 4] = o;
}

// ============ K8: inter pipeline (fused): QH2-proj + inter attn + moving + score =========
// 512 blocks x 256 thr, 8 cands/block. chid packed fp16-transposed so one b128 feeds
// 4 cands; score phase uses BOTH half-waves (lane<32 -> cand w, lane>=32 -> cand w+4).
__global__ __launch_bounds__(256) void k_inter_pipe(const float* inter_w1, const float* inter_out,
                                                    const float* score_w, float* ws, float* d_out) {
  __shared__ float Ks[32][260];
  __shared__ float Hs[32][260];
  __shared__ unsigned int ctdh[128][12];   // [k2][c]: pack(chid[c][2k2], chid[c][2k2+1])
  __shared__ float qh2s[8][260];
  __shared__ float Io[260];
  __shared__ float aw[8][36];
  int blk = blockIdx.x, tid = threadIdx.x;
  int bId0 = blk * 8;
  int w = tid >> 6, lane = tid & 63;

  for (int i = tid; i < 32 * 256; i += 256) {
    int t = i >> 8, d = i & 255;
    Ks[t][d] = ws[OFF_KH2 + t * 256 + d];
    Hs[t][d] = ws[OFF_HIST + t * 256 + d];
  }
  for (int i = tid; i < 8 * 128; i += 256) {
    int c = i >> 7, k2 = i & 127;
    float2 v = *(const float2*)&ws[OFF_CHID + (bId0 + c) * 256 + k2 * 2];
    ctdh[k2][c] = packh(v.x, v.y);
  }
  Io[tid] = inter_out[tid];
  __syncthreads();

  // qh2[c][tid] = relu(chid[c] . w1[tid])
  float acc[8];
  #pragma unroll
  for (int c = 0; c < 8; ++c) acc[c] = 0.f;
  const float* wr = inter_w1 + tid * 256;
  for (int k = 0; k < 256; k += 4) {
    float4 wv = *(const float4*)(wr + k);
    unsigned int w01 = packh(wv.x, wv.y), w23 = packh(wv.z, wv.w);
    int k2 = k >> 1;
    uint4 xa = *(const uint4*)&ctdh[k2][0];
    uint4 xb = *(const uint4*)&ctdh[k2][4];
    uint4 xc = *(const uint4*)&ctdh[k2 + 1][0];
    uint4 xd = *(const uint4*)&ctdh[k2 + 1][4];
    acc[0] = fdot2f(w01, xa.x, acc[0]); acc[0] = fdot2f(w23, xc.x, acc[0]);
    acc[1] = fdot2f(w01, xa.y, acc[1]); acc[1] = fdot2f(w23, xc.y, acc[1]);
    acc[2] = fdot2f(w01, xa.z, acc[2]); acc[2] = fdot2f(w23, xc.z, acc[2]);
    acc[3] = fdot2f(w01, xa.w, acc[3]); acc[3] = fdot2f(w23, xc.w, acc[3]);
    acc[4] = fdot2f(w01, xb.x, acc[4]); acc[4] = fdot2f(w23, xd.x, acc[4]);
    acc[5] = fdot2f(w01, xb.y, acc[5]); acc[5] = fdot2f(w23, xd.y, acc[5]);
    acc[6] = fdot2f(w01, xb.z, acc[6]); acc[6] = fdot2f(w23, xd.z, acc[6]);
    acc[7] = fdot2f(w01, xb.w, acc[7]); acc[7] = fdot2f(w23, xd.w, acc[7]);
  }
  #pragma unroll
  for (int c = 0; c < 8; ++c) qh2s[c][tid] = fmaxf(acc[c], 0.f);
  __syncthreads();

  // scores: lane<32 -> cand w (row lane); lane>=32 -> cand w+4 (row lane-32)
  {
    int c = (lane < 32) ? w : (w + 4);
    int t = lane & 31;
    float p = 0.f;
    for (int d = 0; d < 256; d += 4) {
      float4 k4 = *(const float4*)&Ks[t][d];
      float4 q4 = *(const float4*)&qh2s[c][d];
      float4 i4 = *(const float4*)&Io[d];
      p += tanhf_fast(q4.x + k4.x) * i4.x + tanhf_fast(q4.y + k4.y) * i4.y +
           tanhf_fast(q4.z + k4.z) * i4.z + tanhf_fast(q4.w + k4.w) * i4.w;
    }
    float m = p;
    #pragma unroll
    for (int off = 16; off; off >>= 1) m = fmaxf(m, __shfl_xor(m, off, 32));
    float e = __expf(p - m);
    float ssum = e;
    #pragma unroll
    for (int off = 16; off; off >>= 1) ssum += __shfl_xor(ssum, off, 32);
    aw[c][t] = e / ssum;
  }
  __syncthreads();

  // moving + score for cands w and w+4
  float4 sw = *(const float4*)&score_w[lane * 4];
  #pragma unroll
  for (int cc = 0; cc < 2; ++cc) {
    int c = w + cc * 4;
    float ax = 0.f, ay = 0.f, az = 0.f, az2 = 0.f;
    for (int t = 0; t < 32; ++t) {
      float wt2 = aw[c][t];
      float4 hv = *(const float4*)&Hs[t][lane * 4];
      ax += wt2 * hv.x; ay += wt2 * hv.y; az += wt2 * hv.z; az2 += wt2 * hv.w;
    }
    float4 o; o.x = ax; o.y = ay; o.z = az; o.w = az2;
    *(float4*)&d_out[4096 + (bId0 + c) * 256 + lane * 4] = o;
    float sc = ax*sw.x + ay*sw.y + az*sw.z + az2*sw.w;
    #pragma unroll
    for (int off = 32; off; off >>= 1) sc += __shfl_xor(sc, off);
    if (lane == 0) ws[OFF_SC + bId0 + c] = sc;
  }
}

// ================= K9: probs = softmax over C=128 per s ==================================
__global__ __launch_bounds__(64) void k_probs(const float* ws, float* d_out) {
  int s = blockIdx.x, lane = threadIdx.x;
  float v0 = ws[OFF_SC + s * 128 + lane];
  float v1 = ws[OFF_SC + s * 128 + 64 + lane];
  float m = fmaxf(v0, v1);
  #pragma unroll
  for (int off = 32; off; off >>= 1) m = fmaxf(m, __shfl_xor(m, off));
  float e0 = __expf(v0 - m), e1 = __expf(v1 - m);
  float ssum = e0 + e1;
  #pragma unroll
  for (int off = 32; off; off >>= 1) ssum += __shfl_xor(ssum, off);
  float inv = 1.f / ssum;
  d_out[s * 128 + lane] = e0 * inv;
  d_out[s * 128 + 64 + lane] = e1 * inv;
}

// ======================= launch =========================================================
extern "C" void kernel_launch(void* const* d_in, const int* in_sizes, int n_in,
                              void* d_out, int out_size, void* d_ws, size_t ws_size,
                              hipStream_t stream) {
  const int*   uid      = (const int*)  d_in[0];
  const int*   cur_tr   = (const int*)  d_in[1];
  const int*   hist_tr  = (const int*)  d_in[2];
  const int*   cand_set = (const int*)  d_in[3];
  const float* uid_emb  = (const float*)d_in[4];
  const float* loc_emb  = (const float*)d_in[5];
  const float* wde      = (const float*)d_in[6];
  const float* hre      = (const float*)d_in[7];
  const float* W_ih     = (const float*)d_in[8];
  const float* W_hh     = (const float*)d_in[9];
  const float* b_ih     = (const float*)d_in[10];
  const float* b_hh     = (const float*)d_in[11];
  const float* intra_w1 = (const float*)d_in[12];
  const float* intra_w2 = (const float*)d_in[13];
  const float* intra_out= (const float*)d_in[14];
  const float* inter_w1 = (const float*)d_in[15];
  const float* inter_w2 = (const float*)d_in[16];
  const float* inter_out= (const float*)d_in[17];
  const float* score_w  = (const float*)d_in[18];
  float* ws  = (float*)d_ws;
  float* out = (float*)d_out;

  hipLaunchKernelGGL(k_prep,       dim3(128),  dim3(256), 0, stream, uid, uid_emb, wde, hre, W_ih, b_ih, W_hh, ws);
  hipLaunchKernelGGL(k_xproj,      dim3(192),  dim3(256), 0, stream, cur_tr, hist_tr, loc_emb, W_ih, ws);
  hipLaunchKernelGGL(k_gru,        dim3(64),   dim3(768), 0, stream, b_hh, intra_w1, ws);
  hipLaunchKernelGGL(k_cand,       dim3(256),  dim3(256), 0, stream, cur_tr, cand_set, loc_emb, W_ih, ws);
  hipLaunchKernelGGL(k_proj_intra, dim3(352),  dim3(256), 0, stream, intra_w1, intra_w2, ws);
  hipLaunchKernelGGL(k_hist_attn,  dim3(32),   dim3(256), 0, stream, intra_out, inter_w2, ws);
  hipLaunchKernelGGL(k_cand_attn,  dim3(1024), dim3(256), 0, stream, intra_out, ws);
  hipLaunchKernelGGL(k_inter_pipe, dim3(512),  dim3(256), 0, stream, inter_w1, inter_out, score_w, ws, out);
  hipLaunchKernelGGL(k_probs,      dim3(32),   dim3(64),  0, stream, ws, out);
}